// Round 10
// baseline (141.348 us; speedup 1.0000x reference)
//
#include <hip/hip_runtime.h>
#include <hip/hip_bf16.h>

// ---------------- problem constants ----------------
#define NN 50000
#define NE 800000
#define NF 128
#define NB 196        // ceil(NN/256) buckets of 256 nodes
#define BSH 8         // bucket = dst >> 8
#define BNODES 256
#define GTILES 3125   // NN / 16 row-tiles (exact)

typedef __attribute__((ext_vector_type(8))) short bf16x8;
typedef __attribute__((ext_vector_type(4))) float f32x4;
union Frag { uint4 u; bf16x8 v; };

__device__ __forceinline__ unsigned bf16rne(float f) {
    unsigned u = __float_as_uint(f);
    return (u + 0x7FFFu + ((u >> 16) & 1u)) >> 16;
}
__device__ __forceinline__ unsigned pk2(float lo, float hi) {
    __hip_bfloat162 h = __float22bfloat162_rn(float2{lo, hi});
    unsigned r; __builtin_memcpy(&r, &h, 4); return r;
}
__device__ __forceinline__ float blo(unsigned u) { return __uint_as_float(u << 16); }
__device__ __forceinline__ float bhi(unsigned u) { return __uint_as_float(u & 0xffff0000u); }

// ---------------- K0: zero the bucket histogram ----------------
__global__ void zero_kernel(unsigned* __restrict__ hist) {
    if (threadIdx.x < NB) hist[threadIdx.x] = 0;
}

// ---------------- K1: bucket histogram (LDS-binned) ----------------
__global__ __launch_bounds__(256) void hist_kernel(const int* __restrict__ ei,
                                                   unsigned* __restrict__ hist, int E) {
    __shared__ unsigned lh[NB];
    if (threadIdx.x < NB) lh[threadIdx.x] = 0;
    __syncthreads();
    const int base = blockIdx.x * 4096;
#pragma unroll
    for (int j = 0; j < 16; ++j) {
        int e = base + j * 256 + threadIdx.x;
        if (e < E) atomicAdd(&lh[(unsigned)ei[E + e] >> BSH], 1u);
    }
    __syncthreads();
    if (threadIdx.x < NB && lh[threadIdx.x]) atomicAdd(&hist[threadIdx.x], lh[threadIdx.x]);
}

// ---------------- K2: one-wave exclusive scan over NB bucket counts ----------------
__global__ void bscan_kernel(const unsigned* __restrict__ hist, unsigned* __restrict__ boff,
                             unsigned* __restrict__ gcursor, int* __restrict__ row_ptr) {
    int lane = threadIdx.x & 63;
    unsigned v[4]; unsigned s = 0;
#pragma unroll
    for (int j = 0; j < 4; ++j) {
        int i = lane * 4 + j;
        v[j] = (i < NB) ? hist[i] : 0u;
        s += v[j];
    }
    unsigned e = s;
    for (int d = 1; d < 64; d <<= 1) {
        unsigned t = __shfl_up(e, d, 64);
        if (lane >= d) e += t;
    }
    e -= s;
    unsigned run = e;
#pragma unroll
    for (int j = 0; j < 4; ++j) {
        int i = lane * 4 + j;
        if (i < NB) { boff[i] = run; gcursor[i] = run; }
        run += v[j];
    }
    if (lane == 63) row_ptr[NN] = (int)run;
}

// ---------------- K3: bucketed scatter, LDS-staged chunk claims ----------------
__global__ __launch_bounds__(256) void scatter_kernel(const int* __restrict__ ei,
                                                      unsigned* __restrict__ gcursor,
                                                      unsigned* __restrict__ bedge, int E) {
    __shared__ unsigned rec[8192];
    __shared__ unsigned char bkt[8192];
    __shared__ unsigned lh[NB], cb[NB], lh2[NB];
    const int t = threadIdx.x;
    if (t < NB) { lh[t] = 0; lh2[t] = 0; }
    __syncthreads();
    const int base = blockIdx.x * 8192;
    const int cnt = min(8192, E - base);
#pragma unroll
    for (int j = 0; j < 32; ++j) {
        int k = j * 256 + t;
        if (k < cnt) {
            int e = base + k;
            unsigned s = (unsigned)ei[e];
            unsigned d = (unsigned)ei[E + e];
            unsigned b = d >> BSH;
            rec[k] = (s << 8) | (d & 255u);
            bkt[k] = (unsigned char)b;
            atomicAdd(&lh[b], 1u);
        }
    }
    __syncthreads();
    if (t < NB) cb[t] = lh[t] ? atomicAdd(&gcursor[t], lh[t]) : 0u;
    __syncthreads();
#pragma unroll
    for (int j = 0; j < 32; ++j) {
        int k = j * 256 + t;
        if (k < cnt) {
            unsigned b = bkt[k];
            unsigned r = atomicAdd(&lh2[b], 1u);
            bedge[cb[b] + r] = rec[k];
        }
    }
}

// ---------------- K4: per-bucket CSR build + deg + dis ----------------
__global__ __launch_bounds__(256) void csr_kernel(const unsigned* __restrict__ bedge,
                                                  const unsigned* __restrict__ boff,
                                                  const unsigned* __restrict__ bend,
                                                  int* __restrict__ row_ptr,
                                                  float* __restrict__ dis,
                                                  unsigned short* __restrict__ esrc) {
    __shared__ unsigned cnt[BNODES], woff[BNODES], cur[BNODES];
    __shared__ unsigned srec[8192];
    __shared__ unsigned short sout[8192];
    const int b = blockIdx.x;
    const unsigned base = boff[b];
    const unsigned end  = bend[b];
    const int ecnt = (int)(end - base);
    const int n0 = b * BNODES;
    const int nCnt = min(BNODES, NN - n0);
    const int t = threadIdx.x;
    cnt[t] = 0;
    __syncthreads();

    const bool fast = (ecnt <= 8192);
    if (fast) {
        for (int k = t; k < ecnt; k += 256) {
            unsigned r = bedge[base + k];
            srec[k] = r;
            atomicAdd(&cnt[r & 255u], 1u);
        }
    } else {
        for (int k = t; k < ecnt; k += 256) atomicAdd(&cnt[bedge[base + k] & 255u], 1u);
    }
    __syncthreads();
    if (t < 64) {
        unsigned v[4]; unsigned s = 0;
#pragma unroll
        for (int j = 0; j < 4; ++j) { v[j] = cnt[t * 4 + j]; s += v[j]; }
        unsigned e = s;
        for (int d = 1; d < 64; d <<= 1) {
            unsigned x = __shfl_up(e, d, 64);
            if (t >= d) e += x;
        }
        e -= s;
        unsigned run = e;
#pragma unroll
        for (int j = 0; j < 4; ++j) { woff[t * 4 + j] = run; run += v[j]; }
    }
    __syncthreads();
    if (t < nCnt) {
        row_ptr[n0 + t] = (int)(base + woff[t]);
        dis[n0 + t] = rsqrtf((float)(cnt[t] + 1u));
    }
    cur[t] = 0;
    __syncthreads();
    if (fast) {
        for (int k = t; k < ecnt; k += 256) {
            unsigned r = srec[k];
            unsigned dl = r & 255u;
            unsigned p = woff[dl] + atomicAdd(&cur[dl], 1u);
            sout[p] = (unsigned short)(r >> 8);
        }
        __syncthreads();
        for (int k = t; k < ecnt; k += 256) esrc[base + k] = sout[k];
    } else {
        for (int k = t; k < ecnt; k += 256) {
            unsigned r = bedge[base + k];
            unsigned dl = r & 255u;
            unsigned p = woff[dl] + atomicAdd(&cur[dl], 1u);
            esrc[base + p] = (unsigned short)(r >> 8);
        }
    }
}

// ---------------- GEMM: H1 = x @ W1 via MFMA bf16 (fp32 accum) ----------------
__global__ __launch_bounds__(256, 2) void gemm1_kernel(const float* __restrict__ x,
                                                       const float* __restrict__ W1,
                                                       unsigned short* __restrict__ H1u,
                                                       int nRows) {
    __shared__ __align__(16) unsigned short w1t[128 * 128];  // 32KB bf16 [c][k] swizzled
    const int t = threadIdx.x;
    const int lane = t & 63;
    const int wid = t >> 6;

    {
        const int c = t & 127;
        const int kb0 = (t >> 7) * 8;
        char* wb = reinterpret_cast<char*>(w1t);
        for (int jj = 0; jj < 8; ++jj) {
            int k0 = kb0 + jj * 16;
            unsigned u0 = pk2(W1[(k0 + 0) * NF + c], W1[(k0 + 1) * NF + c]);
            unsigned u1 = pk2(W1[(k0 + 2) * NF + c], W1[(k0 + 3) * NF + c]);
            unsigned u2 = pk2(W1[(k0 + 4) * NF + c], W1[(k0 + 5) * NF + c]);
            unsigned u3 = pk2(W1[(k0 + 6) * NF + c], W1[(k0 + 7) * NF + c]);
            int off = (c * 256 + k0 * 2) ^ ((c & 7) << 4);
            *reinterpret_cast<uint4*>(wb + off) = make_uint4(u0, u1, u2, u3);
        }
    }
    __syncthreads();

    const int col = lane & 15;
    const int kb  = lane >> 4;   // 0..3
    const int cw  = wid * 32;
    Frag bfr[2][4];
    {
        const char* wb = reinterpret_cast<const char*>(w1t);
#pragma unroll
        for (int ct = 0; ct < 2; ++ct) {
            int c = cw + ct * 16 + col;
#pragma unroll
            for (int ks = 0; ks < 4; ++ks) {
                int k0 = ks * 32 + kb * 8;
                int off = (c * 256 + k0 * 2) ^ ((c & 7) << 4);
                bfr[ct][ks].u = *reinterpret_cast<const uint4*>(wb + off);
            }
        }
    }

    const int row = lane & 15;
    for (int tile = blockIdx.x; tile < GTILES; tile += gridDim.x) {
        const int rb = tile * 16;
        const float* xr = x + (size_t)(rb + row) * NF + kb * 8;
        Frag a[4];
#pragma unroll
        for (int ks = 0; ks < 4; ++ks) {
            float4 q0 = *reinterpret_cast<const float4*>(xr + ks * 32);
            float4 q1 = *reinterpret_cast<const float4*>(xr + ks * 32 + 4);
            a[ks].u = make_uint4(pk2(q0.x, q0.y), pk2(q0.z, q0.w),
                                 pk2(q1.x, q1.y), pk2(q1.z, q1.w));
        }
        f32x4 acc0 = {0.f, 0.f, 0.f, 0.f};
        f32x4 acc1 = {0.f, 0.f, 0.f, 0.f};
#pragma unroll
        for (int ks = 0; ks < 4; ++ks) {
            acc0 = __builtin_amdgcn_mfma_f32_16x16x32_bf16(a[ks].v, bfr[0][ks].v, acc0, 0, 0, 0);
            acc1 = __builtin_amdgcn_mfma_f32_16x16x32_bf16(a[ks].v, bfr[1][ks].v, acc1, 0, 0, 0);
        }
        const int orow = rb + (lane >> 4) * 4;
#pragma unroll
        for (int r = 0; r < 4; ++r) {
            H1u[(size_t)(orow + r) * NF + cw + col]      = (unsigned short)bf16rne(acc0[r]);
            H1u[(size_t)(orow + r) * NF + cw + 16 + col] = (unsigned short)bf16rne(acc1[r]);
        }
    }
}

// ---------------- fused layer1, XCD-sliced: slice s handles feats [32s,32s+32) ----------------
// slice = (blockIdx&7)>>1 pins each feature slice (3.2MB of H1b) to one XCD pair's L2.
// One wave per (node, slice). 8-lane groups x uint2 -> 8 edges per gather instr.
// Writes partial zp[s*N + v] = sum_k relu(h_k) * W2[k] over the slice.
__global__ __launch_bounds__(256) void layer1s_kernel(const unsigned* __restrict__ H1b,
                                                      const unsigned short* __restrict__ esrc,
                                                      const int* __restrict__ row_ptr,
                                                      const float* __restrict__ dis,
                                                      const float* __restrict__ b1,
                                                      const float* __restrict__ W2,
                                                      float* __restrict__ zp, int N) {
    const int bid = blockIdx.x;
    const int slice = (bid & 7) >> 1;
    const int nb = ((bid >> 3) << 1) | (bid & 1);       // per-slice block seq [0,12500)
    const int wid = threadIdx.x >> 6;
    const int v = nb * 4 + wid;
    if (v >= N) return;
    const int lane = threadIdx.x & 63;
    const int grp = lane >> 3;                          // 8 edge-groups of 8 lanes
    const int sub = lane & 7;                           // feats slice*32 + sub*4 .. +4
    const char* hb = reinterpret_cast<const char*>(H1b);
    const size_t soff = (size_t)slice * 64 + sub * 8;   // byte offset in 256B row

    const int base = row_ptr[v];
    const int end  = row_ptr[v + 1];

    float a[4] = {0.f, 0.f, 0.f, 0.f};

    for (int cb = base; cb < end; cb += 64) {
        int es = 0; float ds_ = 0.f;
        if (cb + lane < end) {
            es = esrc[cb + lane];                       // coalesced ushort
            ds_ = dis[es];
        }
        const int m = min(64, end - cb);
        const int ng = (m + 7) >> 3;                    // 8-edge groups
        int i = 0;
        for (; i + 2 <= ng; i += 2) {                   // 16 edges in flight
            float w[2]; uint2 u[2];
#pragma unroll
            for (int j = 0; j < 2; ++j) {
                int idx = 8 * (i + j) + grp;
                int sj = __shfl(es, idx);
                w[j] = __shfl(ds_, idx);
                u[j] = *reinterpret_cast<const uint2*>(hb + (size_t)(unsigned)sj * 256 + soff);
            }
#pragma unroll
            for (int j = 0; j < 2; ++j) {
                a[0] = fmaf(blo(u[j].x), w[j], a[0]);
                a[1] = fmaf(bhi(u[j].x), w[j], a[1]);
                a[2] = fmaf(blo(u[j].y), w[j], a[2]);
                a[3] = fmaf(bhi(u[j].y), w[j], a[3]);
            }
        }
        for (; i < ng; ++i) {
            int idx = 8 * i + grp;
            int sj = __shfl(es, idx);
            float wj = __shfl(ds_, idx);
            uint2 uj = *reinterpret_cast<const uint2*>(hb + (size_t)(unsigned)sj * 256 + soff);
            a[0] = fmaf(blo(uj.x), wj, a[0]);
            a[1] = fmaf(bhi(uj.x), wj, a[1]);
            a[2] = fmaf(blo(uj.y), wj, a[2]);
            a[3] = fmaf(bhi(uj.y), wj, a[3]);
        }
    }

    // fold the 8 groups (disjoint edges, same features)
#pragma unroll
    for (int k = 0; k < 4; ++k) {
        a[k] += __shfl_xor(a[k], 8, 64);
        a[k] += __shfl_xor(a[k], 16, 64);
        a[k] += __shfl_xor(a[k], 32, 64);
    }

    const float dv = dis[v];
    const float sw = dv * dv;
    uint2 hs = *reinterpret_cast<const uint2*>(hb + (size_t)v * 256 + soff);
    float hf[4] = { blo(hs.x), bhi(hs.x), blo(hs.y), bhi(hs.y) };
    float4 bb = *reinterpret_cast<const float4*>(b1 + slice * 32 + sub * 4);
    float4 w2 = *reinterpret_cast<const float4*>(W2 + slice * 32 + sub * 4);
    float bbv[4] = { bb.x, bb.y, bb.z, bb.w };
    float w2v[4] = { w2.x, w2.y, w2.z, w2.w };

    float p = 0.f;
#pragma unroll
    for (int k = 0; k < 4; ++k) {
        float h = fmaf(dv, a[k], fmaf(sw, hf[k], bbv[k]));
        h = h > 0.f ? h : 0.f;
        p = fmaf(h, w2v[k], p);
    }
    p += __shfl_xor(p, 1, 64);
    p += __shfl_xor(p, 2, 64);
    p += __shfl_xor(p, 4, 64);
    if (lane == 0) zp[(size_t)slice * N + v] = p;
}

// ---------------- combine the 4 slice partials: zd = dis * sum(zp) ----------------
__global__ void zcomb_kernel(const float* __restrict__ zp, const float* __restrict__ dis,
                             float* __restrict__ zd, int N) {
    int v = blockIdx.x * 256 + threadIdx.x;
    if (v < N) zd[v] = dis[v] * (zp[v] + zp[N + v] + zp[2 * N + v] + zp[3 * N + v]);
}

// ---------------- layer2 aggregate (scalar zd gather) + finalize ----------------
__global__ __launch_bounds__(256) void final_kernel(const float* __restrict__ zd,
                                                    const unsigned short* __restrict__ esrc,
                                                    const int* __restrict__ row_ptr,
                                                    const float* __restrict__ dis,
                                                    const float* __restrict__ b2,
                                                    float* __restrict__ out, int N) {
    const int g = (blockIdx.x * 256 + threadIdx.x) >> 3;
    if (g >= N) return;
    const int sl = threadIdx.x & 7;
    const int base = row_ptr[g];
    const int end  = row_ptr[g + 1];
    float acc = 0.f;
    for (int e = base + sl; e < end; e += 8) acc += zd[esrc[e]];
#pragma unroll
    for (int d = 1; d < 8; d <<= 1) acc += __shfl_xor(acc, d, 64);
    if (sl == 0) out[g] = fmaf(dis[g], acc + zd[g], b2[0]);
}

// ---------------- launch ----------------
extern "C" void kernel_launch(void* const* d_in, const int* in_sizes, int n_in,
                              void* d_out, int out_size, void* d_ws, size_t ws_size,
                              hipStream_t stream) {
    const float* x  = (const float*)d_in[0];
    const int*   ei = (const int*)d_in[1];
    const float* W1 = (const float*)d_in[2];
    const float* b1 = (const float*)d_in[3];
    const float* W2 = (const float*)d_in[4];
    const float* b2 = (const float*)d_in[5];
    float* out = (float*)d_out;

    char* ws = (char*)d_ws;
    size_t o = 0;
    auto alloc = [&](size_t bytes) -> void* {
        void* p = ws + o;
        o += (bytes + 255) & ~(size_t)255;
        return p;
    };
    unsigned* hist    = (unsigned*)alloc((size_t)NB * 4);
    unsigned* boff    = (unsigned*)alloc((size_t)(NB + 1) * 4);
    unsigned* gcursor = (unsigned*)alloc((size_t)NB * 4);
    float*    dis     = (float*)alloc((size_t)NN * 4);
    int*      row_ptr = (int*)alloc((size_t)(NN + 1) * 4);
    unsigned* bedge   = (unsigned*)alloc((size_t)NE * 4);
    unsigned short* esrc = (unsigned short*)alloc((size_t)NE * 2);
    float*    zd      = (float*)alloc((size_t)NN * 4);
    float*    zp      = (float*)alloc((size_t)NN * 4 * 4);
    unsigned* H1b     = (unsigned*)alloc((size_t)NN * NF * 2);  // bf16, row stride 256B

    zero_kernel<<<1, 256, 0, stream>>>(hist);
    hist_kernel<<<(NE + 4095) / 4096, 256, 0, stream>>>(ei, hist, NE);
    bscan_kernel<<<1, 64, 0, stream>>>(hist, boff, gcursor, row_ptr);
    scatter_kernel<<<(NE + 8191) / 8192, 256, 0, stream>>>(ei, gcursor, bedge, NE);
    csr_kernel<<<NB, 256, 0, stream>>>(bedge, boff, gcursor, row_ptr, dis, esrc);

    gemm1_kernel<<<784, 256, 0, stream>>>(x, W1, (unsigned short*)H1b, NN);

    layer1s_kernel<<<50000, 256, 0, stream>>>(H1b, esrc, row_ptr, dis, b1, W2, zp, NN);
    zcomb_kernel<<<(NN + 255) / 256, 256, 0, stream>>>(zp, dis, zd, NN);

    final_kernel<<<(NN * 8 + 255) / 256, 256, 0, stream>>>(zd, esrc, row_ptr, dis, b2, out, NN);
}

// Round 11
// 92.924 us; speedup vs baseline: 1.5211x; 1.5211x over previous
//
#include <hip/hip_runtime.h>
#include <hip/hip_bf16.h>

// ---------------- problem constants ----------------
#define NN 50000
#define NE 800000
#define NF 128
#define NB 196        // ceil(NN/256) buckets of 256 nodes
#define BSH 8         // bucket = dst >> 8
#define BNODES 256
#define GTILES 3125   // NN / 16 row-tiles (exact)
#define HBLK 196      // hist blocks in fused kernel
#define GBLK 784      // gemm blocks in fused kernel

typedef __attribute__((ext_vector_type(8))) short bf16x8;
typedef __attribute__((ext_vector_type(4))) float f32x4;
union Frag { uint4 u; bf16x8 v; };

__device__ __forceinline__ unsigned bf16rne(float f) {
    unsigned u = __float_as_uint(f);
    return (u + 0x7FFFu + ((u >> 16) & 1u)) >> 16;
}
__device__ __forceinline__ unsigned pk2(float lo, float hi) {
    __hip_bfloat162 h = __float22bfloat162_rn(float2{lo, hi});
    unsigned r; __builtin_memcpy(&r, &h, 4); return r;
}
__device__ __forceinline__ float blo(unsigned u) { return __uint_as_float(u << 16); }
__device__ __forceinline__ float bhi(unsigned u) { return __uint_as_float(u & 0xffff0000u); }

// ---------------- K0: zero the bucket histogram ----------------
__global__ void zero_kernel(unsigned* __restrict__ hist) {
    if (threadIdx.x < NB) hist[threadIdx.x] = 0;
}

// ---------------- K1 fused: blocks [0,196) = LDS-binned histogram;
//                  blocks [196,980) = MFMA GEMM H1=x@W1 (independent work) ----------------
__global__ __launch_bounds__(256, 2) void histgemm_kernel(const int* __restrict__ ei,
                                                          unsigned* __restrict__ hist,
                                                          const float* __restrict__ x,
                                                          const float* __restrict__ W1,
                                                          unsigned short* __restrict__ H1u,
                                                          int E) {
    __shared__ unsigned lh[NB];
    __shared__ __align__(16) unsigned short w1t[128 * 128];  // 32KB bf16 [c][k] swizzled
    const int t = threadIdx.x;

    if (blockIdx.x < HBLK) {
        // ---------- histogram part ----------
        if (t < NB) lh[t] = 0;
        __syncthreads();
        const int base = blockIdx.x * 4096;
#pragma unroll
        for (int j = 0; j < 16; ++j) {
            int e = base + j * 256 + t;
            if (e < E) atomicAdd(&lh[(unsigned)ei[E + e] >> BSH], 1u);
        }
        __syncthreads();
        if (t < NB && lh[t]) atomicAdd(&hist[t], lh[t]);
        return;
    }

    // ---------- GEMM part ----------
    const int lane = t & 63;
    const int wid = t >> 6;

    {   // stage W1 -> bf16 [c][k], XOR-swizzled
        const int c = t & 127;
        const int kb0 = (t >> 7) * 8;
        char* wb = reinterpret_cast<char*>(w1t);
        for (int jj = 0; jj < 8; ++jj) {
            int k0 = kb0 + jj * 16;
            unsigned u0 = pk2(W1[(k0 + 0) * NF + c], W1[(k0 + 1) * NF + c]);
            unsigned u1 = pk2(W1[(k0 + 2) * NF + c], W1[(k0 + 3) * NF + c]);
            unsigned u2 = pk2(W1[(k0 + 4) * NF + c], W1[(k0 + 5) * NF + c]);
            unsigned u3 = pk2(W1[(k0 + 6) * NF + c], W1[(k0 + 7) * NF + c]);
            int off = (c * 256 + k0 * 2) ^ ((c & 7) << 4);
            *reinterpret_cast<uint4*>(wb + off) = make_uint4(u0, u1, u2, u3);
        }
    }
    __syncthreads();

    const int col = lane & 15;
    const int kb  = lane >> 4;   // 0..3
    const int cw  = wid * 32;
    Frag bfr[2][4];
    {
        const char* wb = reinterpret_cast<const char*>(w1t);
#pragma unroll
        for (int ct = 0; ct < 2; ++ct) {
            int c = cw + ct * 16 + col;
#pragma unroll
            for (int ks = 0; ks < 4; ++ks) {
                int k0 = ks * 32 + kb * 8;
                int off = (c * 256 + k0 * 2) ^ ((c & 7) << 4);
                bfr[ct][ks].u = *reinterpret_cast<const uint4*>(wb + off);
            }
        }
    }

    const int row = lane & 15;
    for (int tile = blockIdx.x - HBLK; tile < GTILES; tile += GBLK) {
        const int rb = tile * 16;
        const float* xr = x + (size_t)(rb + row) * NF + kb * 8;
        Frag a[4];
#pragma unroll
        for (int ks = 0; ks < 4; ++ks) {
            float4 q0 = *reinterpret_cast<const float4*>(xr + ks * 32);
            float4 q1 = *reinterpret_cast<const float4*>(xr + ks * 32 + 4);
            a[ks].u = make_uint4(pk2(q0.x, q0.y), pk2(q0.z, q0.w),
                                 pk2(q1.x, q1.y), pk2(q1.z, q1.w));
        }
        f32x4 acc0 = {0.f, 0.f, 0.f, 0.f};
        f32x4 acc1 = {0.f, 0.f, 0.f, 0.f};
#pragma unroll
        for (int ks = 0; ks < 4; ++ks) {
            acc0 = __builtin_amdgcn_mfma_f32_16x16x32_bf16(a[ks].v, bfr[0][ks].v, acc0, 0, 0, 0);
            acc1 = __builtin_amdgcn_mfma_f32_16x16x32_bf16(a[ks].v, bfr[1][ks].v, acc1, 0, 0, 0);
        }
        // C/D layout: col = lane&15, row = (lane>>4)*4 + reg  [m89-verified]
        const int orow = rb + (lane >> 4) * 4;
#pragma unroll
        for (int r = 0; r < 4; ++r) {
            H1u[(size_t)(orow + r) * NF + cw + col]      = (unsigned short)bf16rne(acc0[r]);
            H1u[(size_t)(orow + r) * NF + cw + 16 + col] = (unsigned short)bf16rne(acc1[r]);
        }
    }
}

// ---------------- K2: one-wave exclusive scan over NB bucket counts ----------------
__global__ void bscan_kernel(const unsigned* __restrict__ hist, unsigned* __restrict__ boff,
                             unsigned* __restrict__ gcursor, int* __restrict__ row_ptr) {
    int lane = threadIdx.x & 63;
    unsigned v[4]; unsigned s = 0;
#pragma unroll
    for (int j = 0; j < 4; ++j) {
        int i = lane * 4 + j;
        v[j] = (i < NB) ? hist[i] : 0u;
        s += v[j];
    }
    unsigned e = s;
    for (int d = 1; d < 64; d <<= 1) {
        unsigned t = __shfl_up(e, d, 64);
        if (lane >= d) e += t;
    }
    e -= s;
    unsigned run = e;
#pragma unroll
    for (int j = 0; j < 4; ++j) {
        int i = lane * 4 + j;
        if (i < NB) { boff[i] = run; gcursor[i] = run; }
        run += v[j];
    }
    if (lane == 63) row_ptr[NN] = (int)run;
}

// ---------------- K3: bucketed scatter, LDS-staged chunk claims ----------------
__global__ __launch_bounds__(256) void scatter_kernel(const int* __restrict__ ei,
                                                      unsigned* __restrict__ gcursor,
                                                      unsigned* __restrict__ bedge, int E) {
    __shared__ unsigned rec[8192];
    __shared__ unsigned char bkt[8192];
    __shared__ unsigned lh[NB], cb[NB], lh2[NB];
    const int t = threadIdx.x;
    if (t < NB) { lh[t] = 0; lh2[t] = 0; }
    __syncthreads();
    const int base = blockIdx.x * 8192;
    const int cnt = min(8192, E - base);
#pragma unroll
    for (int j = 0; j < 32; ++j) {
        int k = j * 256 + t;
        if (k < cnt) {
            int e = base + k;
            unsigned s = (unsigned)ei[e];
            unsigned d = (unsigned)ei[E + e];
            unsigned b = d >> BSH;
            rec[k] = (s << 8) | (d & 255u);
            bkt[k] = (unsigned char)b;
            atomicAdd(&lh[b], 1u);
        }
    }
    __syncthreads();
    if (t < NB) cb[t] = lh[t] ? atomicAdd(&gcursor[t], lh[t]) : 0u;
    __syncthreads();
#pragma unroll
    for (int j = 0; j < 32; ++j) {
        int k = j * 256 + t;
        if (k < cnt) {
            unsigned b = bkt[k];
            unsigned r = atomicAdd(&lh2[b], 1u);
            bedge[cb[b] + r] = rec[k];
        }
    }
}

// ---------------- K4: per-bucket CSR build + deg + dis ----------------
__global__ __launch_bounds__(256) void csr_kernel(const unsigned* __restrict__ bedge,
                                                  const unsigned* __restrict__ boff,
                                                  const unsigned* __restrict__ bend,
                                                  int* __restrict__ row_ptr,
                                                  float* __restrict__ dis,
                                                  unsigned short* __restrict__ esrc) {
    __shared__ unsigned cnt[BNODES], woff[BNODES], cur[BNODES];
    __shared__ unsigned srec[8192];
    __shared__ unsigned short sout[8192];
    const int b = blockIdx.x;
    const unsigned base = boff[b];
    const unsigned end  = bend[b];
    const int ecnt = (int)(end - base);
    const int n0 = b * BNODES;
    const int nCnt = min(BNODES, NN - n0);
    const int t = threadIdx.x;
    cnt[t] = 0;
    __syncthreads();

    const bool fast = (ecnt <= 8192);
    if (fast) {
        for (int k = t; k < ecnt; k += 256) {
            unsigned r = bedge[base + k];
            srec[k] = r;
            atomicAdd(&cnt[r & 255u], 1u);
        }
    } else {
        for (int k = t; k < ecnt; k += 256) atomicAdd(&cnt[bedge[base + k] & 255u], 1u);
    }
    __syncthreads();
    if (t < 64) {
        unsigned v[4]; unsigned s = 0;
#pragma unroll
        for (int j = 0; j < 4; ++j) { v[j] = cnt[t * 4 + j]; s += v[j]; }
        unsigned e = s;
        for (int d = 1; d < 64; d <<= 1) {
            unsigned x = __shfl_up(e, d, 64);
            if (t >= d) e += x;
        }
        e -= s;
        unsigned run = e;
#pragma unroll
        for (int j = 0; j < 4; ++j) { woff[t * 4 + j] = run; run += v[j]; }
    }
    __syncthreads();
    if (t < nCnt) {
        row_ptr[n0 + t] = (int)(base + woff[t]);
        dis[n0 + t] = rsqrtf((float)(cnt[t] + 1u));
    }
    cur[t] = 0;
    __syncthreads();
    if (fast) {
        for (int k = t; k < ecnt; k += 256) {
            unsigned r = srec[k];
            unsigned dl = r & 255u;
            unsigned p = woff[dl] + atomicAdd(&cur[dl], 1u);
            sout[p] = (unsigned short)(r >> 8);
        }
        __syncthreads();
        for (int k = t; k < ecnt; k += 256) esrc[base + k] = sout[k];
    } else {
        for (int k = t; k < ecnt; k += 256) {
            unsigned r = bedge[base + k];
            unsigned dl = r & 255u;
            unsigned p = woff[dl] + atomicAdd(&cur[dl], 1u);
            esrc[base + p] = (unsigned short)(r >> 8);
        }
    }
}

// ---------------- fused layer1: quarter-wave (16 lanes x b128) per edge [R9] ----------------
__global__ __launch_bounds__(256) void layer1_kernel(const unsigned* __restrict__ H1b,
                                                     const unsigned short* __restrict__ esrc,
                                                     const int* __restrict__ row_ptr,
                                                     const float* __restrict__ dis,
                                                     const float* __restrict__ b1,
                                                     const float* __restrict__ W2,
                                                     float* __restrict__ zd, int N) {
    const int v = (blockIdx.x * 256 + threadIdx.x) >> 6;
    if (v >= N) return;
    const int lane = threadIdx.x & 63;
    const int quad = lane >> 4;        // 0..3: which edge of a quad-group
    const int s16  = lane & 15;        // feature group: feats [s16*8, s16*8+8)
    const int base = row_ptr[v];
    const int end  = row_ptr[v + 1];
    const char* hb = reinterpret_cast<const char*>(H1b);

    float a[8];
#pragma unroll
    for (int k = 0; k < 8; ++k) a[k] = 0.f;

    for (int cb = base; cb < end; cb += 64) {
        const int m = min(64, end - cb);
        int es = 0; float ds_ = 0.f;
        if (cb + lane < end) {
            es = esrc[cb + lane];
            ds_ = dis[es];
        }
        const int nq = (m + 3) >> 2;
        int i = 0;
        for (; i + 4 <= nq; i += 4) {              // 16 edges in flight
            float w[4]; uint4 u[4];
#pragma unroll
            for (int j = 0; j < 4; ++j) {
                int idx = 4 * (i + j) + quad;
                int sj = __shfl(es, idx);
                w[j] = __shfl(ds_, idx);
                u[j] = *reinterpret_cast<const uint4*>(hb + (size_t)(unsigned)sj * 256 + s16 * 16);
            }
#pragma unroll
            for (int j = 0; j < 4; ++j) {
                a[0] = fmaf(blo(u[j].x), w[j], a[0]);
                a[1] = fmaf(bhi(u[j].x), w[j], a[1]);
                a[2] = fmaf(blo(u[j].y), w[j], a[2]);
                a[3] = fmaf(bhi(u[j].y), w[j], a[3]);
                a[4] = fmaf(blo(u[j].z), w[j], a[4]);
                a[5] = fmaf(bhi(u[j].z), w[j], a[5]);
                a[6] = fmaf(blo(u[j].w), w[j], a[6]);
                a[7] = fmaf(bhi(u[j].w), w[j], a[7]);
            }
        }
        for (; i < nq; ++i) {
            int idx = 4 * i + quad;
            int sj = __shfl(es, idx);
            float wj = __shfl(ds_, idx);
            uint4 uj = *reinterpret_cast<const uint4*>(hb + (size_t)(unsigned)sj * 256 + s16 * 16);
            a[0] = fmaf(blo(uj.x), wj, a[0]);
            a[1] = fmaf(bhi(uj.x), wj, a[1]);
            a[2] = fmaf(blo(uj.y), wj, a[2]);
            a[3] = fmaf(bhi(uj.y), wj, a[3]);
            a[4] = fmaf(blo(uj.z), wj, a[4]);
            a[5] = fmaf(bhi(uj.z), wj, a[5]);
            a[6] = fmaf(blo(uj.w), wj, a[6]);
            a[7] = fmaf(bhi(uj.w), wj, a[7]);
        }
    }

#pragma unroll
    for (int k = 0; k < 8; ++k) {
        a[k] += __shfl_xor(a[k], 16, 64);
        a[k] += __shfl_xor(a[k], 32, 64);
    }

    const float dv = dis[v];
    const float sw = dv * dv;
    uint4 hs = *reinterpret_cast<const uint4*>(hb + (size_t)v * 256 + s16 * 16);
    float hf[8] = { blo(hs.x), bhi(hs.x), blo(hs.y), bhi(hs.y),
                    blo(hs.z), bhi(hs.z), blo(hs.w), bhi(hs.w) };
    float4 bb0 = *reinterpret_cast<const float4*>(b1 + s16 * 8);
    float4 bb1 = *reinterpret_cast<const float4*>(b1 + s16 * 8 + 4);
    float4 w20 = *reinterpret_cast<const float4*>(W2 + s16 * 8);
    float4 w21 = *reinterpret_cast<const float4*>(W2 + s16 * 8 + 4);
    float bbv[8] = { bb0.x, bb0.y, bb0.z, bb0.w, bb1.x, bb1.y, bb1.z, bb1.w };
    float w2v[8] = { w20.x, w20.y, w20.z, w20.w, w21.x, w21.y, w21.z, w21.w };

    float p = 0.f;
#pragma unroll
    for (int k = 0; k < 8; ++k) {
        float h = fmaf(dv, a[k], fmaf(sw, hf[k], bbv[k]));
        h = h > 0.f ? h : 0.f;
        p = fmaf(h, w2v[k], p);
    }
    p += __shfl_xor(p, 1, 64);
    p += __shfl_xor(p, 2, 64);
    p += __shfl_xor(p, 4, 64);
    p += __shfl_xor(p, 8, 64);
    if (lane == 0) zd[v] = dv * p;
}

// ---------------- layer2 aggregate (scalar zd gather) + finalize ----------------
__global__ __launch_bounds__(256) void final_kernel(const float* __restrict__ zd,
                                                    const unsigned short* __restrict__ esrc,
                                                    const int* __restrict__ row_ptr,
                                                    const float* __restrict__ dis,
                                                    const float* __restrict__ b2,
                                                    float* __restrict__ out, int N) {
    const int g = (blockIdx.x * 256 + threadIdx.x) >> 3;
    if (g >= N) return;
    const int sl = threadIdx.x & 7;
    const int base = row_ptr[g];
    const int end  = row_ptr[g + 1];
    float acc = 0.f;
    for (int e = base + sl; e < end; e += 8) acc += zd[esrc[e]];
#pragma unroll
    for (int d = 1; d < 8; d <<= 1) acc += __shfl_xor(acc, d, 64);
    if (sl == 0) out[g] = fmaf(dis[g], acc + zd[g], b2[0]);
}

// ---------------- launch ----------------
extern "C" void kernel_launch(void* const* d_in, const int* in_sizes, int n_in,
                              void* d_out, int out_size, void* d_ws, size_t ws_size,
                              hipStream_t stream) {
    const float* x  = (const float*)d_in[0];
    const int*   ei = (const int*)d_in[1];
    const float* W1 = (const float*)d_in[2];
    const float* b1 = (const float*)d_in[3];
    const float* W2 = (const float*)d_in[4];
    const float* b2 = (const float*)d_in[5];
    float* out = (float*)d_out;

    char* ws = (char*)d_ws;
    size_t o = 0;
    auto alloc = [&](size_t bytes) -> void* {
        void* p = ws + o;
        o += (bytes + 255) & ~(size_t)255;
        return p;
    };
    unsigned* hist    = (unsigned*)alloc((size_t)NB * 4);
    unsigned* boff    = (unsigned*)alloc((size_t)(NB + 1) * 4);
    unsigned* gcursor = (unsigned*)alloc((size_t)NB * 4);
    float*    dis     = (float*)alloc((size_t)NN * 4);
    int*      row_ptr = (int*)alloc((size_t)(NN + 1) * 4);
    unsigned* bedge   = (unsigned*)alloc((size_t)NE * 4);
    unsigned short* esrc = (unsigned short*)alloc((size_t)NE * 2);
    float*    zd      = (float*)alloc((size_t)NN * 4);
    unsigned* H1b     = (unsigned*)alloc((size_t)NN * NF * 2);  // bf16, row stride 256B

    zero_kernel<<<1, 256, 0, stream>>>(hist);
    histgemm_kernel<<<HBLK + GBLK, 256, 0, stream>>>(ei, hist, x, W1,
                                                     (unsigned short*)H1b, NE);
    bscan_kernel<<<1, 64, 0, stream>>>(hist, boff, gcursor, row_ptr);
    scatter_kernel<<<(NE + 8191) / 8192, 256, 0, stream>>>(ei, gcursor, bedge, NE);
    csr_kernel<<<NB, 256, 0, stream>>>(bedge, boff, gcursor, row_ptr, dis, esrc);

    layer1_kernel<<<(NN * 64 + 255) / 256, 256, 0, stream>>>(H1b, esrc, row_ptr, dis, b1, W2, zd, NN);

    final_kernel<<<(NN * 8 + 255) / 256, 256, 0, stream>>>(zd, esrc, row_ptr, dis, b2, out, NN);
}